// Round 5
// baseline (245.266 us; speedup 1.0000x reference)
//
#include <hip/hip_runtime.h>
#include <hip/hip_bf16.h>

// Problem: B=256, T=256, C=384, H=64, MAX_REL=3 (causal -> rel idx 0..3 only)
// Round 5:
//   qkv: x staged via global_load_lds DMA (saturates HBM; VGPR loads cap at
//        ~1.7 TB/s by Little's law), W via padded LDS (L2-hot). 2 blocks/CU.
//   attn: one block per batch; k/vT staged to LDS once; 4 barrier-free
//        per-wave q-tiles; E via MFMA+shuffle; band-prob w2 identity.

typedef __attribute__((ext_vector_type(8))) __bf16 bf16x8;
typedef __attribute__((ext_vector_type(8))) short short8;
typedef __attribute__((ext_vector_type(4))) float f32x4;
typedef __attribute__((ext_vector_type(4))) int   i32x4;

#define MFMA16(A, B, C) __builtin_amdgcn_mfma_f32_16x16x32_bf16((A), (B), (C), 0, 0, 0)

__device__ __forceinline__ unsigned short f2bf(float f) {
    unsigned int u = __builtin_bit_cast(unsigned int, f);
    u = (u + 0x7FFFu + ((u >> 16) & 1u)) >> 16;   // RNE
    return (unsigned short)u;
}
__device__ __forceinline__ float bf2f(unsigned short s) {
    unsigned int u = ((unsigned int)s) << 16;
    return __builtin_bit_cast(float, u);
}
__device__ __forceinline__ bf16x8 ld16(const unsigned short* p) {
    return __builtin_bit_cast(bf16x8, *(const i32x4*)p);
}

typedef __attribute__((address_space(1))) const unsigned int GU32;
typedef __attribute__((address_space(3))) unsigned int LU32;
__device__ __forceinline__ void dma16(const void* g, void* l) {
    // async global->LDS, 16 B per lane; LDS dest = uniform base + lane*16
    __builtin_amdgcn_global_load_lds((GU32*)g, (LU32*)l, 16, 0, 0);
}

// ---------------------------------------------------------------------------
// Kernel 0: Wt[3][64][384] bf16 (W^T) + Rk[16][64] bf16 (rel_k rows 0..3, rest 0)
// ---------------------------------------------------------------------------
__global__ void prep_wt(const float* __restrict__ Wq, const float* __restrict__ Wk,
                        const float* __restrict__ Wv, const float* __restrict__ relk,
                        unsigned short* __restrict__ Wt, unsigned short* __restrict__ Rk) {
    int i = blockIdx.x * 256 + threadIdx.x;
    if (i < 3 * 64 * 384) {
        int kk = i % 384;
        int h  = (i / 384) & 63;
        int w  = i / (384 * 64);
        const float* W = (w == 0) ? Wq : ((w == 1) ? Wk : Wv);
        Wt[i] = f2bf(W[kk * 64 + h]);
    } else if (i < 3 * 64 * 384 + 1024) {
        int j = i - 3 * 64 * 384;
        int n = j >> 6, h = j & 63;
        Rk[j] = (n < 4) ? f2bf(relk[n * 64 + h]) : (unsigned short)0;
    }
}

// ---------------------------------------------------------------------------
// Kernel 1: QKV projection. Grid 1024 x 256 thr (4 waves), 64 rows/block.
//   4 chunks of 96 k. Per chunk: x tile [64][96]f32 via DMA (XOR-swizzled
//   unpadded LDS), W tile [192 rows][96 k] via VGPR loads into padded LDS
//   (stride 100 u16 -> bank-spread). LDS 62976 B -> 2 blocks/CU.
// ---------------------------------------------------------------------------
__global__ __launch_bounds__(256, 2) void qkv_kernel(
        const float* __restrict__ x, const unsigned short* __restrict__ Wt,
        unsigned short* __restrict__ q, unsigned short* __restrict__ k,
        unsigned short* __restrict__ vT) {
    __shared__ float xs[64 * 96];                 // 24576 B, swizzled pieces
    __shared__ unsigned short ws[192 * 100];      // 38400 B, padded rows

    const int tid  = threadIdx.x;
    const int wave = tid >> 6;
    const int lane = tid & 63;
    const int c    = lane & 15;
    const int quad = lane >> 4;
    const int row0 = blockIdx.x * 64;

    f32x4 zero = {0.f, 0.f, 0.f, 0.f};
    f32x4 aq[4], ak[4], av[4];
#pragma unroll
    for (int i = 0; i < 4; i++) { aq[i] = zero; ak[i] = zero; av[i] = zero; }

    const int rloc = wave * 16 + c;               // lane's local x row

    for (int ck = 0; ck < 4; ck++) {
        if (ck) __syncthreads();                  // prev chunk reads done
        // x DMA: 24 wave-instrs/block = 6/wave; piece swizzle q = p ^ (r&7) in 8-groups
#pragma unroll
        for (int s = 0; s < 6; s++) {
            int flat = (wave * 6 + s) * 64 + lane;     // piece index [0,1536)
            int r  = flat / 24;
            int qq = flat % 24;
            int p  = (qq & ~7) | ((qq & 7) ^ (r & 7));
            const float* g = x + (size_t)(row0 + r) * 384 + ck * 96 + p * 4;
            dma16(g, xs + (size_t)(wave * 6 + s) * 256);
        }
        // W stage: 2304 pieces, 9/thread (L2-hot)
#pragma unroll
        for (int it = 0; it < 9; it++) {
            int P = it * 256 + tid;
            int r = P / 12, pc = P % 12;
            i32x4 d = *(const i32x4*)(Wt + r * 384 + ck * 96 + pc * 8);
            *(i32x4*)(ws + r * 100 + pc * 8) = d;
        }
        __syncthreads();                          // drains DMA (vmcnt) + LDS writes

#pragma unroll
        for (int ks = 0; ks < 3; ks++) {
            // swizzled x reads -> bf16 A-frag
            int p0 = ks * 8 + quad * 2;
            int q0 = (p0 & ~7) | ((p0 & 7) ^ (rloc & 7));
            int p1 = p0 + 1;
            int q1 = (p1 & ~7) | ((p1 & 7) ^ (rloc & 7));
            f32x4 x0 = *(const f32x4*)(xs + rloc * 96 + q0 * 4);
            f32x4 x1 = *(const f32x4*)(xs + rloc * 96 + q1 * 4);
            short8 xs8;
#pragma unroll
            for (int j = 0; j < 4; j++) {
                xs8[j]     = (short)f2bf(x0[j]);
                xs8[4 + j] = (short)f2bf(x1[j]);
            }
            bf16x8 a = __builtin_bit_cast(bf16x8, xs8);

#pragma unroll
            for (int nt = 0; nt < 4; nt++) {
                bf16x8 bq = ld16(ws + (nt * 16 + c) * 100 + (ks * 4 + quad) * 8);
                bf16x8 bk = ld16(ws + (64 + nt * 16 + c) * 100 + (ks * 4 + quad) * 8);
                bf16x8 aw = ld16(ws + (128 + nt * 16 + c) * 100 + (ks * 4 + quad) * 8);
                aq[nt] = MFMA16(a, bq, aq[nt]);    // D[t][h]
                ak[nt] = MFMA16(a, bk, ak[nt]);    // D[t][h]
                av[nt] = MFMA16(aw, a, av[nt]);    // D[h][t] (swapped operands)
            }
        }
    }

    // epilogue: C/D layout col=lane&15, row=quad*4+reg
    const int b   = row0 >> 8;
    const int t0b = row0 & 255;
#pragma unroll
    for (int nt = 0; nt < 4; nt++) {
#pragma unroll
        for (int r = 0; r < 4; r++) {
            int row = row0 + wave * 16 + quad * 4 + r;
            q[row * 64 + nt * 16 + c] = f2bf(aq[nt][r]);
            k[row * 64 + nt * 16 + c] = f2bf(ak[nt][r]);
            int h = nt * 16 + quad * 4 + r;
            vT[(b * 64 + h) * 256 + t0b + wave * 16 + c] = f2bf(av[nt][r]);
        }
    }
}

// ---------------------------------------------------------------------------
// Kernel 2: attention. ONE block (256 thr, 4 waves) per batch, grid 256.
//   Stage k[b] ([256][68] u16 padded) + vT[b] ([64][264] u16 padded) once.
//   Wave w handles q-tiles tt = w, w+4, w+8, w+12 with NO block barriers:
//   wave-private P rows + s_waitcnt lgkmcnt(0) fence; E via MFMA + shuffles.
//   Unnormalized exp (scores bounded, r4-verified); 1/l folded into epilogue.
// LDS: kb 34816 | vb 33792 | Pb 4x16x264 u16 33792  = 102400 B (1 block/CU)
// ---------------------------------------------------------------------------
__global__ __launch_bounds__(256) void attn_kernel(
        const unsigned short* __restrict__ q, const unsigned short* __restrict__ kg,
        const unsigned short* __restrict__ vT, const unsigned short* __restrict__ Rk,
        const float* __restrict__ relv, float* __restrict__ out) {
    extern __shared__ char smem[];
    unsigned short* kb = (unsigned short*)(smem);            // [256][68]
    unsigned short* vb = (unsigned short*)(smem + 34816);    // [64][264]
    unsigned short* Pb = (unsigned short*)(smem + 68608);    // [4][16][264]

    const int tid  = threadIdx.x;
    const int wave = tid >> 6;
    const int lane = tid & 63;
    const int c    = lane & 15;
    const int quad = lane >> 4;
    const int b    = blockIdx.x;

    f32x4 zero = {0.f, 0.f, 0.f, 0.f};

    // stage k[b]: 2048 pieces of 16 B, 8/thread
#pragma unroll
    for (int it = 0; it < 8; it++) {
        int P = it * 256 + tid;
        int r = P >> 3, pc = P & 7;
        i32x4 d = *(const i32x4*)(kg + ((size_t)b * 256 + r) * 64 + pc * 8);
        *(i32x4*)(kb + r * 68 + pc * 8) = d;
    }
    // stage vT[b]: 2048 pieces, 8/thread
#pragma unroll
    for (int it = 0; it < 8; it++) {
        int P = it * 256 + tid;
        int r = P >> 5, pc = P & 31;
        i32x4 d = *(const i32x4*)(vT + ((size_t)b * 64 + r) * 256 + pc * 8);
        *(i32x4*)(vb + r * 264 + pc * 8) = d;
    }
    __syncthreads();

    // per-lane invariants
    bf16x8 rk0 = ld16(Rk + c * 64 + quad * 8);
    bf16x8 rk1 = ld16(Rk + c * 64 + 32 + quad * 8);
    float rv[4][4];
#pragma unroll
    for (int j = 0; j < 4; j++)
#pragma unroll
        for (int nt = 0; nt < 4; nt++) rv[j][nt] = relv[j * 64 + nt * 16 + c];
    unsigned short* Pw = Pb + wave * 16 * 264;               // wave-private

    for (int ti = 0; ti < 4; ti++) {
        const int tt  = ti * 4 + wave;
        const int t0  = tt * 16;
        const int nst = tt + 1;

        const unsigned short* qp = q + (size_t)(b * 256 + t0 + c) * 64 + quad * 8;
        bf16x8 aq0 = ld16(qp);
        bf16x8 aq1 = ld16(qp + 32);

        // E[m][j] = q_{t0+m} . relk_j via MFMA; broadcast via quad shuffles
        f32x4 e = MFMA16(aq0, rk0, zero);
        e = MFMA16(aq1, rk1, e);
        float ef[4][4];
#pragma unroll
        for (int r = 0; r < 4; r++)
#pragma unroll
            for (int j = 0; j < 4; j++)
                ef[r][j] = __shfl(e[r], (lane & 48) | j, 64);

        // scores -> unnormalized exp -> wave-private LDS; row sums in regs
        float l[4] = {0.f, 0.f, 0.f, 0.f};
        for (int st = 0; st < nst; st++) {
            int R = st * 16 + c;
            f32x4 s = MFMA16(aq0, ld16(kb + R * 68 + quad * 8), zero);
            s = MFMA16(aq1, ld16(kb + R * 68 + 32 + quad * 8), s);
#pragma unroll
            for (int r = 0; r < 4; r++) {
                int tg = t0 + quad * 4 + r;
                int d  = R - tg;                             // s - t
                float ee = (d <= -3) ? ef[r][0] : (d == -2) ? ef[r][1]
                         : (d == -1) ? ef[r][2] : ef[r][3];
                float p = (d > 0) ? 0.f : __expf(0.125f * (s[r] + ee));
                l[r] += p;
                Pw[(quad * 4 + r) * 264 + R] = f2bf(p);
            }
        }
        if (nst & 1) {                                       // pad odd k-tile
#pragma unroll
            for (int r = 0; r < 4; r++) Pw[(quad * 4 + r) * 264 + nst * 16 + c] = 0;
        }
#pragma unroll
        for (int r = 0; r < 4; r++)
#pragma unroll
            for (int ofs = 1; ofs < 16; ofs <<= 1)
                l[r] += __shfl_xor(l[r], ofs, 64);
        float rl[4];
#pragma unroll
        for (int r = 0; r < 4; r++) rl[r] = 1.0f / l[r];

        __asm__ volatile("s_waitcnt lgkmcnt(0)" ::: "memory");  // P writes visible (wave)

        // O = P^ @ V (A = Pw rows, B = vb rows)
        f32x4 o[4];
#pragma unroll
        for (int nt = 0; nt < 4; nt++) o[nt] = zero;
        const int ksteps = (nst + 1) >> 1;
        for (int ks = 0; ks < ksteps; ks++) {
            bf16x8 ap = ld16(Pw + c * 264 + ks * 32 + quad * 8);
#pragma unroll
            for (int nt = 0; nt < 4; nt++) {
                bf16x8 vf = ld16(vb + (nt * 16 + c) * 264 + ks * 32 + quad * 8);
                o[nt] = MFMA16(ap, vf, o[nt]);
            }
        }

        // epilogue: normalize + band-probability w2 + store
#pragma unroll
        for (int r = 0; r < 4; r++) {
            int tl = quad * 4 + r;
            int tg = t0 + tl;
            float pa = (tg >= 2) ? bf2f(Pw[tl * 264 + tg - 2]) * rl[r] : 0.f;
            float pb = (tg >= 1) ? bf2f(Pw[tl * 264 + tg - 1]) * rl[r] : 0.f;
            float pc = bf2f(Pw[tl * 264 + tg]) * rl[r];
#pragma unroll
            for (int nt = 0; nt < 4; nt++) {
                float r0 = rv[0][nt];
                float w2 = r0 + pa * (rv[1][nt] - r0) + pb * (rv[2][nt] - r0)
                              + pc * (rv[3][nt] - r0);
                out[(size_t)(b * 256 + tg) * 64 + nt * 16 + c] = o[nt][r] * rl[r] + w2;
            }
        }
    }
}

// ---------------------------------------------------------------------------
extern "C" void kernel_launch(void* const* d_in, const int* in_sizes, int n_in,
                              void* d_out, int out_size, void* d_ws, size_t ws_size,
                              hipStream_t stream) {
    const float* x    = (const float*)d_in[0];
    const float* Wq   = (const float*)d_in[1];
    const float* Wk   = (const float*)d_in[2];
    const float* Wv   = (const float*)d_in[3];
    const float* relk = (const float*)d_in[4];
    const float* relv = (const float*)d_in[5];
    float* out = (float*)d_out;

    char* ws = (char*)d_ws;
    unsigned short* q  = (unsigned short*)(ws);                 // 8 MiB
    unsigned short* kk = (unsigned short*)(ws + 8388608);       // 8 MiB
    unsigned short* vT = (unsigned short*)(ws + 16777216);      // 8 MiB
    unsigned short* Wt = (unsigned short*)(ws + 25165824);      // 144 KiB
    unsigned short* Rk = (unsigned short*)(ws + 25313280);      // 2 KiB

    (void)hipFuncSetAttribute((const void*)attn_kernel,
                              hipFuncAttributeMaxDynamicSharedMemorySize, 102400);

    prep_wt<<<292, 256, 0, stream>>>(Wq, Wk, Wv, relk, Wt, Rk);
    qkv_kernel<<<1024, 256, 0, stream>>>(x, Wt, q, kk, vT);
    attn_kernel<<<256, 256, 102400, stream>>>(q, kk, vT, Rk, relv, out);
}

// Round 6
// 205.011 us; speedup vs baseline: 1.1964x; 1.1964x over previous
//
#include <hip/hip_runtime.h>
#include <hip/hip_bf16.h>

// Problem: B=256, T=256, C=384, H=64, MAX_REL=3 (causal -> rel idx 0..3 only)
// Round 6:
//   qkv: W resident in LDS (147 KB, staged ONCE, one barrier), x streamed
//        barrier-free with 1-deep double-buffered register pipeline.
//   attn: r4's one-wave-per-block design + 1-ahead register prefetch of
//        k-frags and vT-frags to hide L2 latency.

typedef __attribute__((ext_vector_type(8))) __bf16 bf16x8;
typedef __attribute__((ext_vector_type(8))) short short8;
typedef __attribute__((ext_vector_type(4))) float f32x4;
typedef __attribute__((ext_vector_type(4))) int   i32x4;

#define MFMA16(A, B, C) __builtin_amdgcn_mfma_f32_16x16x32_bf16((A), (B), (C), 0, 0, 0)

__device__ __forceinline__ unsigned short f2bf(float f) {
    unsigned int u = __builtin_bit_cast(unsigned int, f);
    u = (u + 0x7FFFu + ((u >> 16) & 1u)) >> 16;   // RNE
    return (unsigned short)u;
}
__device__ __forceinline__ float bf2f(unsigned short s) {
    unsigned int u = ((unsigned int)s) << 16;
    return __builtin_bit_cast(float, u);
}
__device__ __forceinline__ bf16x8 ld16(const unsigned short* p) {
    return __builtin_bit_cast(bf16x8, *(const i32x4*)p);
}

// ---------------------------------------------------------------------------
// Kernel 0: Wt[3][64][384] bf16 (W^T) + Rk[16][64] bf16 (rel_k rows 0..3, rest 0)
// ---------------------------------------------------------------------------
__global__ void prep_wt(const float* __restrict__ Wq, const float* __restrict__ Wk,
                        const float* __restrict__ Wv, const float* __restrict__ relk,
                        unsigned short* __restrict__ Wt, unsigned short* __restrict__ Rk) {
    int i = blockIdx.x * 256 + threadIdx.x;
    if (i < 3 * 64 * 384) {
        int kk = i % 384;
        int h  = (i / 384) & 63;
        int w  = i / (384 * 64);
        const float* W = (w == 0) ? Wq : ((w == 1) ? Wk : Wv);
        Wt[i] = f2bf(W[kk * 64 + h]);
    } else if (i < 3 * 64 * 384 + 1024) {
        int j = i - 3 * 64 * 384;
        int n = j >> 6, h = j & 63;
        Rk[j] = (n < 4) ? f2bf(relk[n * 64 + h]) : (unsigned short)0;
    }
}

// ---------------------------------------------------------------------------
// Kernel 1: QKV projection. Grid 512 x 512 thr (8 waves), 128 rows/block.
//   W (all 192 rows x 384 k) staged ONCE into 150 KB dynamic LDS (row stride
//   392 u16 = 196 dw == 4 mod 32: r1's conflict-free class, 16B aligned).
//   ONE barrier total. x path: per wave 24 independent b128 loads, pipelined
//   in 3 chunks of 8 with 1-deep double buffer -> ~8 KB/wave in flight,
//   never drained by vmcnt(0). 1 block/CU (8 waves).
// ---------------------------------------------------------------------------
__global__ __launch_bounds__(512, 1) void qkv_kernel(
        const float* __restrict__ x, const unsigned short* __restrict__ Wt,
        unsigned short* __restrict__ q, unsigned short* __restrict__ k,
        unsigned short* __restrict__ vT) {
    extern __shared__ unsigned short ws[];        // [192][392] u16 = 150528 B

    const int tid  = threadIdx.x;
    const int wave = tid >> 6;
    const int lane = tid & 63;
    const int c    = lane & 15;
    const int quad = lane >> 4;
    const int row0 = blockIdx.x * 128;
    const int myrow = row0 + wave * 16 + c;        // x row owned by this lane

    const float* xp0 = x + (size_t)myrow * 384;

    // issue x chunk-0 loads FIRST (overlap HBM latency with W staging)
    f32x4 xb[2][8];
#pragma unroll
    for (int j = 0; j < 4; j++) {
        xb[0][2 * j]     = *(const f32x4*)(xp0 + j * 32 + quad * 8);
        xb[0][2 * j + 1] = *(const f32x4*)(xp0 + j * 32 + quad * 8 + 4);
    }

    // stage ALL of W: 9216 b128 pieces, 18/thread (L2-hot after gen 0)
#pragma unroll
    for (int it = 0; it < 18; it++) {
        int P = it * 512 + tid;
        int r = P / 48, pc = P % 48;
        i32x4 d = *(const i32x4*)(Wt + r * 384 + pc * 8);
        *(i32x4*)(ws + r * 392 + pc * 8) = d;
    }
    __syncthreads();                               // the ONLY barrier

    f32x4 zero = {0.f, 0.f, 0.f, 0.f};
    f32x4 aq[4], ak[4], av[4];
#pragma unroll
    for (int i = 0; i < 4; i++) { aq[i] = zero; ak[i] = zero; av[i] = zero; }

#pragma unroll
    for (int ck = 0; ck < 3; ck++) {
        const int cur = ck & 1;
        // prefetch next chunk (4 kc x 2 b128) before computing this one
        if (ck < 2) {
#pragma unroll
            for (int j = 0; j < 4; j++) {
                const float* xp = xp0 + (ck + 1) * 128 + j * 32 + quad * 8;
                xb[1 - cur][2 * j]     = *(const f32x4*)xp;
                xb[1 - cur][2 * j + 1] = *(const f32x4*)(xp + 4);
            }
        }
#pragma unroll
        for (int j = 0; j < 4; j++) {
            short8 xs8;
#pragma unroll
            for (int e = 0; e < 4; e++) {
                xs8[e]     = (short)f2bf(xb[cur][2 * j][e]);
                xs8[4 + e] = (short)f2bf(xb[cur][2 * j + 1][e]);
            }
            bf16x8 a = __builtin_bit_cast(bf16x8, xs8);
            const int col = (ck * 4 + j) * 32 + quad * 8;

#pragma unroll
            for (int nt = 0; nt < 4; nt++) {
                bf16x8 bq = ld16(ws + (nt * 16 + c) * 392 + col);
                bf16x8 bk = ld16(ws + (64 + nt * 16 + c) * 392 + col);
                bf16x8 aw = ld16(ws + (128 + nt * 16 + c) * 392 + col);
                aq[nt] = MFMA16(a, bq, aq[nt]);    // D[t][h]
                ak[nt] = MFMA16(a, bk, ak[nt]);    // D[t][h]
                av[nt] = MFMA16(aw, a, av[nt]);    // D[h][t] (swapped operands)
            }
        }
    }

    // epilogue: C/D layout col=lane&15, row=quad*4+reg
    const int b   = row0 >> 8;
    const int t0b = row0 & 255;
#pragma unroll
    for (int nt = 0; nt < 4; nt++) {
#pragma unroll
        for (int r = 0; r < 4; r++) {
            int row = row0 + wave * 16 + quad * 4 + r;
            q[row * 64 + nt * 16 + c] = f2bf(aq[nt][r]);
            k[row * 64 + nt * 16 + c] = f2bf(ak[nt][r]);
            int h = nt * 16 + quad * 4 + r;
            vT[(b * 64 + h) * 256 + t0b + wave * 16 + c] = f2bf(av[nt][r]);
        }
    }
}

// ---------------------------------------------------------------------------
// Kernel 2: attention, ONE WAVE per block (r4-verified) + 1-ahead prefetch.
//   Grid (16, 256): x = 16-row q-tile tt, y = batch. Wave handles q rows
//   [16tt,16tt+16), s in [0,16(tt+1)). Unnormalized exp -> LDS; 1/l folded
//   into epilogue; E via MFMA vs Rk; w2 via band-probability identity.
// ---------------------------------------------------------------------------
__global__ __launch_bounds__(64, 4) void attn_kernel(
        const unsigned short* __restrict__ q, const unsigned short* __restrict__ kg,
        const unsigned short* __restrict__ vT, const unsigned short* __restrict__ Rk,
        const float* __restrict__ relv, float* __restrict__ out) {
    __shared__ unsigned short P[16][264];          // 8448 B (unnormalized P^)
    __shared__ float E[16][4];

    const int lane = threadIdx.x;
    const int c    = lane & 15;
    const int quad = lane >> 4;
    const int tt   = blockIdx.x;
    const int b    = blockIdx.y;
    const int t0   = tt * 16;
    const int nst  = tt + 1;                       // valid 16-wide s-tiles

    f32x4 zero = {0.f, 0.f, 0.f, 0.f};

    // q A-frags: lane's A-row m = c -> q row t0+c
    const unsigned short* qp = q + (size_t)(b * 256 + t0 + c) * 64 + quad * 8;
    bf16x8 aq0 = ld16(qp);
    bf16x8 aq1 = ld16(qp + 32);

    // E via MFMA vs Rk: D[m=quad*4+r][n=c] = q_{t0+m} . relk_n  (n<4 valid)
    {
        f32x4 e = zero;
        e = MFMA16(aq0, ld16(Rk + c * 64 + quad * 8), e);
        e = MFMA16(aq1, ld16(Rk + c * 64 + 32 + quad * 8), e);
        if (c < 4) {
#pragma unroll
            for (int r = 0; r < 4; r++) E[quad * 4 + r][c] = e[r];
        }
    }
    __syncthreads();                               // single wave: cheap
    f32x4 ef[4];
#pragma unroll
    for (int r = 0; r < 4; r++) ef[r] = *(const f32x4*)(&E[quad * 4 + r][0]);

    // relv preload (L2-hot)
    float rv[4][4];
#pragma unroll
    for (int j = 0; j < 4; j++)
#pragma unroll
        for (int nt = 0; nt < 4; nt++) rv[j][nt] = relv[j * 64 + nt * 16 + c];

    // Phase 1: scores -> unnormalized exp -> LDS, 1-ahead k-frag prefetch
    const unsigned short* kbase = kg + (size_t)b * 256 * 64;
    float l[4] = {0.f, 0.f, 0.f, 0.f};
    bf16x8 ka = ld16(kbase + (size_t)c * 64 + quad * 8);
    bf16x8 kb2 = ld16(kbase + (size_t)c * 64 + 32 + quad * 8);
    for (int st = 0; st < nst; st++) {
        bf16x8 na = ka, nb = kb2;
        if (st + 1 < nst) {
            const unsigned short* kp = kbase + (size_t)((st + 1) * 16 + c) * 64 + quad * 8;
            na = ld16(kp);
            nb = ld16(kp + 32);
        }
        f32x4 s = MFMA16(aq0, ka, zero);
        s = MFMA16(aq1, kb2, s);
        int R = st * 16 + c;
#pragma unroll
        for (int r = 0; r < 4; r++) {
            int tg = t0 + quad * 4 + r;
            int d  = R - tg;                       // s - t
            float ee = (d <= -3) ? ef[r][0] : (d == -2) ? ef[r][1]
                     : (d == -1) ? ef[r][2] : ef[r][3];
            float p = (d > 0) ? 0.f : __expf(0.125f * (s[r] + ee));
            l[r] += p;
            P[quad * 4 + r][R] = f2bf(p);
        }
        ka = na; kb2 = nb;
    }
    if (nst & 1) {                                 // pad odd k-tile
#pragma unroll
        for (int r = 0; r < 4; r++) P[quad * 4 + r][nst * 16 + c] = 0;
    }
#pragma unroll
    for (int r = 0; r < 4; r++)
#pragma unroll
        for (int ofs = 1; ofs < 16; ofs <<= 1)
            l[r] += __shfl_xor(l[r], ofs, 64);
    float rl[4];
#pragma unroll
    for (int r = 0; r < 4; r++) rl[r] = 1.0f / l[r];
    __syncthreads();                               // P^ visible (single wave)

    // Phase 2: O = P^ @ V, 1-ahead vT-frag prefetch
    const unsigned short* vbase = vT + (size_t)b * 64 * 256;
    f32x4 o[4];
#pragma unroll
    for (int nt = 0; nt < 4; nt++) o[nt] = zero;
    const int ksteps = (nst + 1) >> 1;
    bf16x8 vf[4];
#pragma unroll
    for (int nt = 0; nt < 4; nt++)
        vf[nt] = ld16(vbase + (size_t)(nt * 16 + c) * 256 + quad * 8);
    for (int ks = 0; ks < ksteps; ks++) {
        bf16x8 nv[4];
#pragma unroll
        for (int nt = 0; nt < 4; nt++) nv[nt] = vf[nt];
        if (ks + 1 < ksteps) {
#pragma unroll
            for (int nt = 0; nt < 4; nt++)
                nv[nt] = ld16(vbase + (size_t)(nt * 16 + c) * 256 + (ks + 1) * 32 + quad * 8);
        }
        bf16x8 ap = ld16(&P[c][ks * 32 + quad * 8]);
#pragma unroll
        for (int nt = 0; nt < 4; nt++) o[nt] = MFMA16(ap, vf[nt], o[nt]);
#pragma unroll
        for (int nt = 0; nt < 4; nt++) vf[nt] = nv[nt];
    }

    // epilogue: normalize + band-probability w2 + store
#pragma unroll
    for (int r = 0; r < 4; r++) {
        int tl = quad * 4 + r;
        int tg = t0 + tl;
        float pa = (tg >= 2) ? bf2f(P[tl][tg - 2]) * rl[r] : 0.f;
        float pb = (tg >= 1) ? bf2f(P[tl][tg - 1]) * rl[r] : 0.f;
        float pc = bf2f(P[tl][tg]) * rl[r];
#pragma unroll
        for (int nt = 0; nt < 4; nt++) {
            float r0 = rv[0][nt];
            float w2 = r0 + pa * (rv[1][nt] - r0) + pb * (rv[2][nt] - r0)
                          + pc * (rv[3][nt] - r0);
            out[(size_t)(b * 256 + tg) * 64 + nt * 16 + c] = o[nt][r] * rl[r] + w2;
        }
    }
}

// ---------------------------------------------------------------------------
extern "C" void kernel_launch(void* const* d_in, const int* in_sizes, int n_in,
                              void* d_out, int out_size, void* d_ws, size_t ws_size,
                              hipStream_t stream) {
    const float* x    = (const float*)d_in[0];
    const float* Wq   = (const float*)d_in[1];
    const float* Wk   = (const float*)d_in[2];
    const float* Wv   = (const float*)d_in[3];
    const float* relk = (const float*)d_in[4];
    const float* relv = (const float*)d_in[5];
    float* out = (float*)d_out;

    char* ws = (char*)d_ws;
    unsigned short* q  = (unsigned short*)(ws);                 // 8 MiB
    unsigned short* kk = (unsigned short*)(ws + 8388608);       // 8 MiB
    unsigned short* vT = (unsigned short*)(ws + 16777216);      // 8 MiB
    unsigned short* Wt = (unsigned short*)(ws + 25165824);      // 144 KiB
    unsigned short* Rk = (unsigned short*)(ws + 25313280);      // 2 KiB

    (void)hipFuncSetAttribute((const void*)qkv_kernel,
                              hipFuncAttributeMaxDynamicSharedMemorySize, 150528);

    prep_wt<<<292, 256, 0, stream>>>(Wq, Wk, Wv, relk, Wt, Rk);
    qkv_kernel<<<512, 512, 150528, stream>>>(x, Wt, q, kk, vT);
    attn_kernel<<<dim3(16, 256), 64, 0, stream>>>(q, kk, vT, Rk, relv, out);
}

// Round 7
// 204.981 us; speedup vs baseline: 1.1965x; 1.0001x over previous
//
#include <hip/hip_runtime.h>
#include <hip/hip_bf16.h>

// Problem: B=256, T=256, C=384, H=64, MAX_REL=3 (causal -> rel idx 0..3 only)
// Round 7 (A/B disambiguation, both components at best-known config):
//   qkv: r6 verbatim — W resident in 150 KB LDS staged ONCE (one barrier),
//        x streamed barrier-free with double-buffered register pipeline.
//   attn: r4 verbatim — one wave per block, no global-frag prefetch (the r6
//        prefetch pushed VGPR demand ~148 > launch_bounds(64,4) cap 128 -> spill).

typedef __attribute__((ext_vector_type(8))) __bf16 bf16x8;
typedef __attribute__((ext_vector_type(8))) short short8;
typedef __attribute__((ext_vector_type(4))) float f32x4;
typedef __attribute__((ext_vector_type(4))) int   i32x4;

#define MFMA16(A, B, C) __builtin_amdgcn_mfma_f32_16x16x32_bf16((A), (B), (C), 0, 0, 0)

__device__ __forceinline__ unsigned short f2bf(float f) {
    unsigned int u = __builtin_bit_cast(unsigned int, f);
    u = (u + 0x7FFFu + ((u >> 16) & 1u)) >> 16;   // RNE
    return (unsigned short)u;
}
__device__ __forceinline__ float bf2f(unsigned short s) {
    unsigned int u = ((unsigned int)s) << 16;
    return __builtin_bit_cast(float, u);
}
__device__ __forceinline__ bf16x8 ld16(const unsigned short* p) {
    return __builtin_bit_cast(bf16x8, *(const i32x4*)p);
}

// ---------------------------------------------------------------------------
// Kernel 0: Wt[3][64][384] bf16 (W^T) + Rk[16][64] bf16 (rel_k rows 0..3, rest 0)
// ---------------------------------------------------------------------------
__global__ void prep_wt(const float* __restrict__ Wq, const float* __restrict__ Wk,
                        const float* __restrict__ Wv, const float* __restrict__ relk,
                        unsigned short* __restrict__ Wt, unsigned short* __restrict__ Rk) {
    int i = blockIdx.x * 256 + threadIdx.x;
    if (i < 3 * 64 * 384) {
        int kk = i % 384;
        int h  = (i / 384) & 63;
        int w  = i / (384 * 64);
        const float* W = (w == 0) ? Wq : ((w == 1) ? Wk : Wv);
        Wt[i] = f2bf(W[kk * 64 + h]);
    } else if (i < 3 * 64 * 384 + 1024) {
        int j = i - 3 * 64 * 384;
        int n = j >> 6, h = j & 63;
        Rk[j] = (n < 4) ? f2bf(relk[n * 64 + h]) : (unsigned short)0;
    }
}

// ---------------------------------------------------------------------------
// Kernel 1: QKV projection (r6 verbatim). Grid 512 x 512 thr (8 waves),
//   128 rows/block. W staged ONCE into 150 KB dynamic LDS (row stride 392 u16,
//   conflict-free class). ONE barrier. x: 3 chunks of 8 b128 loads/lane,
//   1-deep double buffer -> no vmcnt(0) drains. 1 block/CU (8 waves).
// ---------------------------------------------------------------------------
__global__ __launch_bounds__(512, 1) void qkv_kernel(
        const float* __restrict__ x, const unsigned short* __restrict__ Wt,
        unsigned short* __restrict__ q, unsigned short* __restrict__ k,
        unsigned short* __restrict__ vT) {
    extern __shared__ unsigned short ws[];        // [192][392] u16 = 150528 B

    const int tid  = threadIdx.x;
    const int wave = tid >> 6;
    const int lane = tid & 63;
    const int c    = lane & 15;
    const int quad = lane >> 4;
    const int row0 = blockIdx.x * 128;
    const int myrow = row0 + wave * 16 + c;        // x row owned by this lane

    const float* xp0 = x + (size_t)myrow * 384;

    // issue x chunk-0 loads FIRST (overlap HBM latency with W staging)
    f32x4 xb[2][8];
#pragma unroll
    for (int j = 0; j < 4; j++) {
        xb[0][2 * j]     = *(const f32x4*)(xp0 + j * 32 + quad * 8);
        xb[0][2 * j + 1] = *(const f32x4*)(xp0 + j * 32 + quad * 8 + 4);
    }

    // stage ALL of W: 9216 b128 pieces, 18/thread (L2-hot)
#pragma unroll
    for (int it = 0; it < 18; it++) {
        int P = it * 512 + tid;
        int r = P / 48, pc = P % 48;
        i32x4 d = *(const i32x4*)(Wt + r * 384 + pc * 8);
        *(i32x4*)(ws + r * 392 + pc * 8) = d;
    }
    __syncthreads();                               // the ONLY barrier

    f32x4 zero = {0.f, 0.f, 0.f, 0.f};
    f32x4 aq[4], ak[4], av[4];
#pragma unroll
    for (int i = 0; i < 4; i++) { aq[i] = zero; ak[i] = zero; av[i] = zero; }

#pragma unroll
    for (int ck = 0; ck < 3; ck++) {
        const int cur = ck & 1;
        // prefetch next chunk before computing this one
        if (ck < 2) {
#pragma unroll
            for (int j = 0; j < 4; j++) {
                const float* xp = xp0 + (ck + 1) * 128 + j * 32 + quad * 8;
                xb[1 - cur][2 * j]     = *(const f32x4*)xp;
                xb[1 - cur][2 * j + 1] = *(const f32x4*)(xp + 4);
            }
        }
#pragma unroll
        for (int j = 0; j < 4; j++) {
            short8 xs8;
#pragma unroll
            for (int e = 0; e < 4; e++) {
                xs8[e]     = (short)f2bf(xb[cur][2 * j][e]);
                xs8[4 + e] = (short)f2bf(xb[cur][2 * j + 1][e]);
            }
            bf16x8 a = __builtin_bit_cast(bf16x8, xs8);
            const int col = (ck * 4 + j) * 32 + quad * 8;

#pragma unroll
            for (int nt = 0; nt < 4; nt++) {
                bf16x8 bq = ld16(ws + (nt * 16 + c) * 392 + col);
                bf16x8 bk = ld16(ws + (64 + nt * 16 + c) * 392 + col);
                bf16x8 aw = ld16(ws + (128 + nt * 16 + c) * 392 + col);
                aq[nt] = MFMA16(a, bq, aq[nt]);    // D[t][h]
                ak[nt] = MFMA16(a, bk, ak[nt]);    // D[t][h]
                av[nt] = MFMA16(aw, a, av[nt]);    // D[h][t] (swapped operands)
            }
        }
    }

    // epilogue: C/D layout col=lane&15, row=quad*4+reg
    const int b   = row0 >> 8;
    const int t0b = row0 & 255;
#pragma unroll
    for (int nt = 0; nt < 4; nt++) {
#pragma unroll
        for (int r = 0; r < 4; r++) {
            int row = row0 + wave * 16 + quad * 4 + r;
            q[row * 64 + nt * 16 + c] = f2bf(aq[nt][r]);
            k[row * 64 + nt * 16 + c] = f2bf(ak[nt][r]);
            int h = nt * 16 + quad * 4 + r;
            vT[(b * 64 + h) * 256 + t0b + wave * 16 + c] = f2bf(av[nt][r]);
        }
    }
}

// ---------------------------------------------------------------------------
// Kernel 2: attention (r4 verbatim), ONE WAVE per block. Grid (16, 256):
//   x = 16-row q-tile, y = batch. Unnormalized exp -> LDS (scores bounded),
//   1/l folded into epilogue; E via MFMA vs Rk; band-prob w2 identity.
// ---------------------------------------------------------------------------
__global__ __launch_bounds__(64, 4) void attn_kernel(
        const unsigned short* __restrict__ q, const unsigned short* __restrict__ k,
        const unsigned short* __restrict__ vT, const unsigned short* __restrict__ Rk,
        const float* __restrict__ relv, float* __restrict__ out) {
    __shared__ unsigned short P[16][264];              // 8448 B (unnormalized P^)
    __shared__ float E[16][4];

    const int lane = threadIdx.x;
    const int c    = lane & 15;
    const int quad = lane >> 4;
    const int tt   = blockIdx.x;
    const int b    = blockIdx.y;
    const int t0   = tt * 16;
    const int nst  = tt + 1;                           // valid 16-wide s-tiles

    f32x4 zero = {0.f, 0.f, 0.f, 0.f};

    // relv preload (L2-hot, 16 coalesced f32 per lane)
    float rv[4][4];
#pragma unroll
    for (int j = 0; j < 4; j++)
#pragma unroll
        for (int nt = 0; nt < 4; nt++) rv[j][nt] = relv[j * 64 + nt * 16 + c];

    // q A-frags: lane's A-row m = c -> q row t0+c
    const unsigned short* qp = q + (size_t)(b * 256 + t0 + c) * 64 + quad * 8;
    bf16x8 aq0 = ld16(qp);
    bf16x8 aq1 = ld16(qp + 32);

    // E via MFMA vs Rk: D[m=quad*4+r][n=c] = q_{t0+m} . relk_n  (n<4 valid)
    {
        f32x4 e = zero;
        e = MFMA16(aq0, ld16(Rk + c * 64 + quad * 8), e);
        e = MFMA16(aq1, ld16(Rk + c * 64 + 32 + quad * 8), e);
        if (c < 4) {
#pragma unroll
            for (int r = 0; r < 4; r++) E[quad * 4 + r][c] = e[r];
        }
    }
    __syncthreads();                                   // single wave: cheap
    f32x4 ef[4];
#pragma unroll
    for (int r = 0; r < 4; r++) ef[r] = *(const f32x4*)(&E[quad * 4 + r][0]);

    // score tiles -> exp -> LDS; accumulate row sums
    float l[4] = {0.f, 0.f, 0.f, 0.f};
#pragma unroll
    for (int st = 0; st < 16; st++) {
        if (st < nst) {
            const unsigned short* kp = k + (size_t)(b * 256 + st * 16 + c) * 64 + quad * 8;
            f32x4 s = zero;
            s = MFMA16(aq0, ld16(kp), s);
            s = MFMA16(aq1, ld16(kp + 32), s);
#pragma unroll
            for (int r = 0; r < 4; r++) {
                int tg = t0 + quad * 4 + r;            // global q row
                int sg = st * 16 + c;                  // global s
                int d  = sg - tg;
                float e = (d <= -3) ? ef[r][0] : (d == -2) ? ef[r][1]
                        : (d == -1) ? ef[r][2] : ef[r][3];
                float p = (d > 0) ? 0.f : __expf(0.125f * (s[r] + e));
                l[r] += p;
                P[quad * 4 + r][sg] = f2bf(p);
            }
        }
    }
    // zero-pad the half-open MFMA k-tile when nst is odd
    if (nst & 1) {
#pragma unroll
        for (int r = 0; r < 4; r++) P[quad * 4 + r][nst * 16 + c] = 0;
    }
    // row-sum over the 16 c-lanes (same quad)
#pragma unroll
    for (int r = 0; r < 4; r++)
#pragma unroll
        for (int ofs = 1; ofs < 16; ofs <<= 1)
            l[r] += __shfl_xor(l[r], ofs, 64);
    float rl[4];
#pragma unroll
    for (int r = 0; r < 4; r++) rl[r] = 1.0f / l[r];
    __syncthreads();                                   // P^ visible (single wave)

    // O = P^ @ V  (A rows m=c from LDS; B = vT rows from global)
    f32x4 o[4];
#pragma unroll
    for (int nt = 0; nt < 4; nt++) o[nt] = zero;
    const int ksteps = (nst + 1) >> 1;
#pragma unroll
    for (int ks = 0; ks < 8; ks++) {
        if (ks < ksteps) {
            bf16x8 ap = ld16(&P[c][ks * 32 + quad * 8]);
#pragma unroll
            for (int nt = 0; nt < 4; nt++) {
                const unsigned short* vp = vT + (size_t)(b * 64 + nt * 16 + c) * 256
                                              + ks * 32 + quad * 8;
                o[nt] = MFMA16(ap, ld16(vp), o[nt]);
            }
        }
    }

    // epilogue: normalize + w2 band-probability identity + store
#pragma unroll
    for (int r = 0; r < 4; r++) {
        int tl = quad * 4 + r;
        int tg = t0 + tl;
        float pa = (tg >= 2) ? bf2f(P[tl][tg - 2]) * rl[r] : 0.f;
        float pb = (tg >= 1) ? bf2f(P[tl][tg - 1]) * rl[r] : 0.f;
        float pc = bf2f(P[tl][tg]) * rl[r];
#pragma unroll
        for (int nt = 0; nt < 4; nt++) {
            float r0 = rv[0][nt];
            float w2 = r0 + pa * (rv[1][nt] - r0) + pb * (rv[2][nt] - r0)
                          + pc * (rv[3][nt] - r0);
            out[(size_t)(b * 256 + tg) * 64 + nt * 16 + c] = o[nt][r] * rl[r] + w2;
        }
    }
}

// ---------------------------------------------------------------------------
extern "C" void kernel_launch(void* const* d_in, const int* in_sizes, int n_in,
                              void* d_out, int out_size, void* d_ws, size_t ws_size,
                              hipStream_t stream) {
    const float* x    = (const float*)d_in[0];
    const float* Wq   = (const float*)d_in[1];
    const float* Wk   = (const float*)d_in[2];
    const float* Wv   = (const float*)d_in[3];
    const float* relk = (const float*)d_in[4];
    const float* relv = (const float*)d_in[5];
    float* out = (float*)d_out;

    char* ws = (char*)d_ws;
    unsigned short* q  = (unsigned short*)(ws);                 // 8 MiB
    unsigned short* kk = (unsigned short*)(ws + 8388608);       // 8 MiB
    unsigned short* vT = (unsigned short*)(ws + 16777216);      // 8 MiB
    unsigned short* Wt = (unsigned short*)(ws + 25165824);      // 144 KiB
    unsigned short* Rk = (unsigned short*)(ws + 25313280);      // 2 KiB

    (void)hipFuncSetAttribute((const void*)qkv_kernel,
                              hipFuncAttributeMaxDynamicSharedMemorySize, 150528);

    prep_wt<<<292, 256, 0, stream>>>(Wq, Wk, Wv, relk, Wt, Rk);
    qkv_kernel<<<512, 512, 150528, stream>>>(x, Wt, q, kk, vT);
    attn_kernel<<<dim3(16, 256), 64, 0, stream>>>(q, kk, vT, Rk, relv, out);
}